// Round 1
// baseline (80.973 us; speedup 1.0000x reference)
//
#include <hip/hip_runtime.h>

#define BB 1024
#define LL 200
#define HH 512
#define NOUT 5
#define BN_EPS 1e-5f

// ---------------- K1: ragged embedding-bag mean pooling ----------------
// One block (256 threads) per example; thread owns 2 consecutive columns.
__global__ __launch_bounds__(256) void pool_kernel(const int* __restrict__ tokens,
                                                   const int* __restrict__ lengths,
                                                   const float* __restrict__ emb,
                                                   float* __restrict__ pooled) {
    __shared__ int toks[LL];
    const int b = blockIdx.x;
    const int tid = threadIdx.x;
    const int len = lengths[b];
    for (int t = tid; t < len; t += 256) toks[t] = tokens[b * LL + t];
    __syncthreads();
    const int c = tid * 2;
    float ax = 0.f, ay = 0.f;
    int t = 0;
    for (; t + 8 <= len; t += 8) {
#pragma unroll
        for (int u = 0; u < 8; ++u) {
            const float2 v = *(const float2*)&emb[(size_t)toks[t + u] * HH + c];
            ax += v.x; ay += v.y;
        }
    }
    for (; t < len; ++t) {
        const float2 v = *(const float2*)&emb[(size_t)toks[t] * HH + c];
        ax += v.x; ay += v.y;
    }
    const float fl = (float)len;
    float2 r; r.x = ax / fl; r.y = ay / fl;
    *(float2*)&pooled[b * HH + c] = r;
}

// ---------------- K2: h_pre = pooled @ W1 + b1  (fp32, LDS-tiled) ------
// BM=64, BN=64, BK=16, 256 threads, 4x4 micro-tile per thread.
__global__ __launch_bounds__(256) void gemm1_kernel(const float* __restrict__ A,
                                                    const float* __restrict__ Bm,
                                                    const float* __restrict__ b1,
                                                    float* __restrict__ C) {
    __shared__ float As[16][65];  // [BK][BM+1] transposed-store
    __shared__ float Bs[16][64];  // [BK][BN]
    const int tid = threadIdx.x;
    const int tx = tid & 15;   // 0..15 -> 4 cols each
    const int ty = tid >> 4;   // 0..15 -> 4 rows each
    const int brow = blockIdx.y * 64;
    const int bcol = blockIdx.x * 64;

    float acc[4][4];
#pragma unroll
    for (int i = 0; i < 4; ++i)
#pragma unroll
        for (int j = 0; j < 4; ++j) acc[i][j] = 0.f;

    for (int k0 = 0; k0 < HH; k0 += 16) {
        // A tile: 64 rows x 16 cols
        {
            const int r = tid >> 2;          // 0..63
            const int cv = (tid & 3) * 4;    // 0,4,8,12
            const float4 a = *(const float4*)&A[(size_t)(brow + r) * HH + k0 + cv];
            As[cv + 0][r] = a.x; As[cv + 1][r] = a.y;
            As[cv + 2][r] = a.z; As[cv + 3][r] = a.w;
        }
        // B tile: 16 rows x 64 cols
        {
            const int r = tid >> 4;          // 0..15
            const int cv = (tid & 15) * 4;   // 0..60
            *(float4*)&Bs[r][cv] = *(const float4*)&Bm[(size_t)(k0 + r) * HH + bcol + cv];
        }
        __syncthreads();
#pragma unroll
        for (int kk = 0; kk < 16; ++kk) {
            const float4 bv = *(const float4*)&Bs[kk][tx * 4];
            const float a0 = As[kk][ty * 4 + 0];
            const float a1 = As[kk][ty * 4 + 1];
            const float a2 = As[kk][ty * 4 + 2];
            const float a3 = As[kk][ty * 4 + 3];
            acc[0][0] += a0 * bv.x; acc[0][1] += a0 * bv.y; acc[0][2] += a0 * bv.z; acc[0][3] += a0 * bv.w;
            acc[1][0] += a1 * bv.x; acc[1][1] += a1 * bv.y; acc[1][2] += a1 * bv.z; acc[1][3] += a1 * bv.w;
            acc[2][0] += a2 * bv.x; acc[2][1] += a2 * bv.y; acc[2][2] += a2 * bv.z; acc[2][3] += a2 * bv.w;
            acc[3][0] += a3 * bv.x; acc[3][1] += a3 * bv.y; acc[3][2] += a3 * bv.z; acc[3][3] += a3 * bv.w;
        }
        __syncthreads();
    }
    const float4 b1v = *(const float4*)&b1[bcol + tx * 4];
#pragma unroll
    for (int c = 0; c < 4; ++c) {
        float4 o;
        o.x = acc[c][0] + b1v.x; o.y = acc[c][1] + b1v.y;
        o.z = acc[c][2] + b1v.z; o.w = acc[c][3] + b1v.w;
        *(float4*)&C[(size_t)(brow + ty * 4 + c) * HH + bcol + tx * 4] = o;
    }
}

// ---------------- K3a: partial column sums / sumsq over 16-row slabs ---
__global__ __launch_bounds__(256) void stats_partial_kernel(const float* __restrict__ Hm,
                                                            float* __restrict__ ps,
                                                            float* __restrict__ pq) {
    const int p = blockIdx.x;     // 64 slabs of 16 rows
    const int tid = threadIdx.x;  // 256 threads, 2 cols each
    const int c = tid * 2;
    float s0 = 0.f, s1 = 0.f, q0 = 0.f, q1 = 0.f;
#pragma unroll 4
    for (int r = 0; r < 16; ++r) {
        const float2 v = *(const float2*)&Hm[(size_t)(p * 16 + r) * HH + c];
        s0 += v.x; s1 += v.y;
        q0 += v.x * v.x; q1 += v.y * v.y;
    }
    float2 s; s.x = s0; s.y = s1;
    float2 q; q.x = q0; q.y = q1;
    *(float2*)&ps[p * HH + c] = s;
    *(float2*)&pq[p * HH + c] = q;
}

// ---------------- K3b: finalize BN -> scale/shift ----------------------
__global__ __launch_bounds__(512) void stats_final_kernel(const float* __restrict__ ps,
                                                          const float* __restrict__ pq,
                                                          const float* __restrict__ gamma,
                                                          const float* __restrict__ beta,
                                                          float* __restrict__ scale,
                                                          float* __restrict__ shift) {
    const int j = threadIdx.x;  // 512
    float S = 0.f, Q = 0.f;
    for (int p = 0; p < 64; ++p) {
        S += ps[p * HH + j];
        Q += pq[p * HH + j];
    }
    const float mu = S * (1.f / (float)BB);
    const float var = Q * (1.f / (float)BB) - mu * mu;
    const float sc = gamma[j] * rsqrtf(var + BN_EPS);
    scale[j] = sc;
    shift[j] = beta[j] - mu * sc;
}

// ---------------- K4: BN + ReLU + GEMM2 (wave-per-row reduce) ----------
__global__ __launch_bounds__(256) void bn_relu_out_kernel(const float* __restrict__ Hm,
                                                          const float* __restrict__ scale,
                                                          const float* __restrict__ shift,
                                                          const float* __restrict__ W2,
                                                          const float* __restrict__ b2,
                                                          float* __restrict__ out) {
    __shared__ float sW2[HH * NOUT];  // 10 KB
    const int tid = threadIdx.x;
#pragma unroll
    for (int i = 0; i < (HH * NOUT) / 256; ++i) sW2[tid + i * 256] = W2[tid + i * 256];
    __syncthreads();
    const int lane = tid & 63;
    const int wave = tid >> 6;
    const int row = blockIdx.x * 4 + wave;
    float a0 = 0.f, a1 = 0.f, a2 = 0.f, a3 = 0.f, a4 = 0.f;
#pragma unroll
    for (int j = 0; j < 8; ++j) {
        const int h = lane + j * 64;  // stride-64 ownership -> stride-5 LDS reads (2-way max)
        float y = Hm[(size_t)row * HH + h] * scale[h] + shift[h];
        y = fmaxf(y, 0.f);
        const float* w = &sW2[h * NOUT];
        a0 += y * w[0]; a1 += y * w[1]; a2 += y * w[2]; a3 += y * w[3]; a4 += y * w[4];
    }
#pragma unroll
    for (int off = 32; off > 0; off >>= 1) {
        a0 += __shfl_down(a0, off, 64);
        a1 += __shfl_down(a1, off, 64);
        a2 += __shfl_down(a2, off, 64);
        a3 += __shfl_down(a3, off, 64);
        a4 += __shfl_down(a4, off, 64);
    }
    if (lane == 0) {
        out[row * NOUT + 0] = a0 + b2[0];
        out[row * NOUT + 1] = a1 + b2[1];
        out[row * NOUT + 2] = a2 + b2[2];
        out[row * NOUT + 3] = a3 + b2[3];
        out[row * NOUT + 4] = a4 + b2[4];
    }
}

extern "C" void kernel_launch(void* const* d_in, const int* in_sizes, int n_in,
                              void* d_out, int out_size, void* d_ws, size_t ws_size,
                              hipStream_t stream) {
    const int*   tokens  = (const int*)d_in[0];
    const int*   lengths = (const int*)d_in[1];
    const float* emb     = (const float*)d_in[2];
    const float* W1      = (const float*)d_in[3];
    const float* b1      = (const float*)d_in[4];
    const float* gamma   = (const float*)d_in[5];
    const float* beta    = (const float*)d_in[6];
    const float* W2      = (const float*)d_in[7];
    const float* b2      = (const float*)d_in[8];
    float* out = (float*)d_out;

    float* ws     = (float*)d_ws;
    float* pooled = ws;                       // 1024*512
    float* hpre   = pooled + BB * HH;         // 1024*512
    float* ps     = hpre + BB * HH;           // 64*512
    float* pq     = ps + 64 * HH;             // 64*512
    float* scale  = pq + 64 * HH;             // 512
    float* shift  = scale + HH;               // 512

    pool_kernel<<<BB, 256, 0, stream>>>(tokens, lengths, emb, pooled);
    gemm1_kernel<<<dim3(HH / 64, BB / 64), 256, 0, stream>>>(pooled, W1, b1, hpre);
    stats_partial_kernel<<<BB / 16, 256, 0, stream>>>(hpre, ps, pq);
    stats_final_kernel<<<1, 512, 0, stream>>>(ps, pq, gamma, beta, scale, shift);
    bn_relu_out_kernel<<<BB / 4, 256, 0, stream>>>(hpre, scale, shift, W2, b2, out);
}

// Round 2
// 76.468 us; speedup vs baseline: 1.0589x; 1.0589x over previous
//
#include <hip/hip_runtime.h>

#define BB 1024
#define LL 200
#define HH 512
#define NOUT 5
#define BN_EPS 1e-5f

// ---------------- K1: ragged embedding-bag mean pooling ----------------
// One block (256 threads) per example. 2 token-groups x 128 threads;
// each thread owns 4 consecutive columns (float4 = 16B/lane).
__global__ __launch_bounds__(256) void pool_kernel(const int* __restrict__ tokens,
                                                   const int* __restrict__ lengths,
                                                   const float* __restrict__ emb,
                                                   float* __restrict__ pooled) {
    __shared__ int toks[LL];
    __shared__ float part[128][4];
    const int b = blockIdx.x;
    const int tid = threadIdx.x;
    const int len = lengths[b];
    for (int t = tid; t < len; t += 256) toks[t] = tokens[b * LL + t];
    __syncthreads();
    const int g = tid >> 7;      // token group 0/1
    const int q = tid & 127;     // column quad
    const int c = q * 4;
    float ax = 0.f, ay = 0.f, az = 0.f, aw = 0.f;
    int t = g;
    for (; t + 14 < len; t += 16) {
#pragma unroll
        for (int u = 0; u < 8; ++u) {
            const float4 v = *(const float4*)&emb[(size_t)toks[t + 2 * u] * HH + c];
            ax += v.x; ay += v.y; az += v.z; aw += v.w;
        }
    }
    for (; t < len; t += 2) {
        const float4 v = *(const float4*)&emb[(size_t)toks[t] * HH + c];
        ax += v.x; ay += v.y; az += v.z; aw += v.w;
    }
    if (g == 1) {
        part[q][0] = ax; part[q][1] = ay; part[q][2] = az; part[q][3] = aw;
    }
    __syncthreads();
    if (g == 0) {
        const float inv = 1.f / (float)len;
        float4 r;
        r.x = (ax + part[q][0]) * inv;
        r.y = (ay + part[q][1]) * inv;
        r.z = (az + part[q][2]) * inv;
        r.w = (aw + part[q][3]) * inv;
        *(float4*)&pooled[b * HH + c] = r;
    }
}

// ---------------- K2: h = pooled @ W1 + b1, fused column stats ---------
// BM=BN=64, BK=16, 256 threads, 4x4 micro-tile. Epilogue reduces per-column
// sum / sumsq across the 64-row tile and atomicAdds into ps/pq[512].
__global__ __launch_bounds__(256) void gemm1_kernel(const float* __restrict__ A,
                                                    const float* __restrict__ Bm,
                                                    const float* __restrict__ b1,
                                                    float* __restrict__ C,
                                                    float* __restrict__ ps,
                                                    float* __restrict__ pq) {
    __shared__ float As[16][68];  // padded: row = 272B, 16B-aligned
    __shared__ float Bs[16][64];
    __shared__ float red[16][64];
    const int tid = threadIdx.x;
    const int tx = tid & 15;
    const int ty = tid >> 4;
    const int brow = blockIdx.y * 64;
    const int bcol = blockIdx.x * 64;

    float acc[4][4];
#pragma unroll
    for (int i = 0; i < 4; ++i)
#pragma unroll
        for (int j = 0; j < 4; ++j) acc[i][j] = 0.f;

    for (int k0 = 0; k0 < HH; k0 += 16) {
        {
            const int r = tid >> 2;
            const int cv = (tid & 3) * 4;
            const float4 a = *(const float4*)&A[(size_t)(brow + r) * HH + k0 + cv];
            As[cv + 0][r] = a.x; As[cv + 1][r] = a.y;
            As[cv + 2][r] = a.z; As[cv + 3][r] = a.w;
        }
        {
            const int r = tid >> 4;
            const int cv = (tid & 15) * 4;
            *(float4*)&Bs[r][cv] = *(const float4*)&Bm[(size_t)(k0 + r) * HH + bcol + cv];
        }
        __syncthreads();
#pragma unroll
        for (int kk = 0; kk < 16; ++kk) {
            const float4 bv = *(const float4*)&Bs[kk][tx * 4];
            const float4 av = *(const float4*)&As[kk][ty * 4];
            acc[0][0] += av.x * bv.x; acc[0][1] += av.x * bv.y; acc[0][2] += av.x * bv.z; acc[0][3] += av.x * bv.w;
            acc[1][0] += av.y * bv.x; acc[1][1] += av.y * bv.y; acc[1][2] += av.y * bv.z; acc[1][3] += av.y * bv.w;
            acc[2][0] += av.z * bv.x; acc[2][1] += av.z * bv.y; acc[2][2] += av.z * bv.z; acc[2][3] += av.z * bv.w;
            acc[3][0] += av.w * bv.x; acc[3][1] += av.w * bv.y; acc[3][2] += av.w * bv.z; acc[3][3] += av.w * bv.w;
        }
        __syncthreads();
    }
    const float4 b1v = *(const float4*)&b1[bcol + tx * 4];
    float sl[4] = {0.f, 0.f, 0.f, 0.f};
    float ql[4] = {0.f, 0.f, 0.f, 0.f};
#pragma unroll
    for (int c = 0; c < 4; ++c) {
        float4 o;
        o.x = acc[c][0] + b1v.x; o.y = acc[c][1] + b1v.y;
        o.z = acc[c][2] + b1v.z; o.w = acc[c][3] + b1v.w;
        *(float4*)&C[(size_t)(brow + ty * 4 + c) * HH + bcol + tx * 4] = o;
        sl[0] += o.x; sl[1] += o.y; sl[2] += o.z; sl[3] += o.w;
        ql[0] += o.x * o.x; ql[1] += o.y * o.y; ql[2] += o.z * o.z; ql[3] += o.w * o.w;
    }
    // column-sum reduce over the 16 ty groups
    *(float4*)&red[ty][tx * 4] = *(float4*)sl;
    __syncthreads();
    if (tid < 64) {
        float S = 0.f;
#pragma unroll
        for (int t = 0; t < 16; ++t) S += red[t][tid];
        atomicAdd(&ps[bcol + tid], S);
    }
    __syncthreads();
    *(float4*)&red[ty][tx * 4] = *(float4*)ql;
    __syncthreads();
    if (tid < 64) {
        float Q = 0.f;
#pragma unroll
        for (int t = 0; t < 16; ++t) Q += red[t][tid];
        atomicAdd(&pq[bcol + tid], Q);
    }
}

// ---------------- K3: BN finalize + ReLU + GEMM2 -----------------------
// Each block recomputes scale/shift from ps/pq (4KB, L2-hot). Wave per row,
// lane owns cols lane+64j; W2 held in registers.
__global__ __launch_bounds__(256) void bn_out_kernel(const float* __restrict__ Hm,
                                                     const float* __restrict__ ps,
                                                     const float* __restrict__ pq,
                                                     const float* __restrict__ gamma,
                                                     const float* __restrict__ beta,
                                                     const float* __restrict__ W2,
                                                     const float* __restrict__ b2,
                                                     float* __restrict__ out) {
    __shared__ float sscale[HH];
    __shared__ float sshift[HH];
    const int tid = threadIdx.x;
#pragma unroll
    for (int i = 0; i < 2; ++i) {
        const int j = tid + i * 256;
        const float mu = ps[j] * (1.f / (float)BB);
        const float var = pq[j] * (1.f / (float)BB) - mu * mu;
        const float sc = gamma[j] * rsqrtf(var + BN_EPS);
        sscale[j] = sc;
        sshift[j] = beta[j] - mu * sc;
    }
    __syncthreads();
    const int lane = tid & 63;
    const int wave = tid >> 6;
    const int row = blockIdx.x * 4 + wave;
    float w[8][NOUT];
#pragma unroll
    for (int j = 0; j < 8; ++j) {
        const int h = lane + j * 64;
#pragma unroll
        for (int k = 0; k < NOUT; ++k) w[j][k] = W2[h * NOUT + k];
    }
    float a0 = 0.f, a1 = 0.f, a2 = 0.f, a3 = 0.f, a4 = 0.f;
#pragma unroll
    for (int j = 0; j < 8; ++j) {
        const int h = lane + j * 64;
        float y = Hm[(size_t)row * HH + h] * sscale[h] + sshift[h];
        y = fmaxf(y, 0.f);
        a0 += y * w[j][0]; a1 += y * w[j][1]; a2 += y * w[j][2];
        a3 += y * w[j][3]; a4 += y * w[j][4];
    }
#pragma unroll
    for (int off = 32; off > 0; off >>= 1) {
        a0 += __shfl_down(a0, off, 64);
        a1 += __shfl_down(a1, off, 64);
        a2 += __shfl_down(a2, off, 64);
        a3 += __shfl_down(a3, off, 64);
        a4 += __shfl_down(a4, off, 64);
    }
    if (lane == 0) {
        out[row * NOUT + 0] = a0 + b2[0];
        out[row * NOUT + 1] = a1 + b2[1];
        out[row * NOUT + 2] = a2 + b2[2];
        out[row * NOUT + 3] = a3 + b2[3];
        out[row * NOUT + 4] = a4 + b2[4];
    }
}

extern "C" void kernel_launch(void* const* d_in, const int* in_sizes, int n_in,
                              void* d_out, int out_size, void* d_ws, size_t ws_size,
                              hipStream_t stream) {
    const int*   tokens  = (const int*)d_in[0];
    const int*   lengths = (const int*)d_in[1];
    const float* emb     = (const float*)d_in[2];
    const float* W1      = (const float*)d_in[3];
    const float* b1      = (const float*)d_in[4];
    const float* gamma   = (const float*)d_in[5];
    const float* beta    = (const float*)d_in[6];
    const float* W2      = (const float*)d_in[7];
    const float* b2      = (const float*)d_in[8];
    float* out = (float*)d_out;

    float* ws     = (float*)d_ws;
    float* pooled = ws;               // 1024*512
    float* hpre   = pooled + BB * HH; // 1024*512
    float* ps     = hpre + BB * HH;   // 512
    float* pq     = ps + HH;          // 512

    hipMemsetAsync(ps, 0, 2 * HH * sizeof(float), stream);
    pool_kernel<<<BB, 256, 0, stream>>>(tokens, lengths, emb, pooled);
    gemm1_kernel<<<dim3(HH / 64, BB / 64), 256, 0, stream>>>(pooled, W1, b1, hpre, ps, pq);
    bn_out_kernel<<<BB / 4, 256, 0, stream>>>(hpre, ps, pq, gamma, beta, W2, b2, out);
}

// Round 3
// 57.355 us; speedup vs baseline: 1.4118x; 1.3332x over previous
//
#include <hip/hip_runtime.h>

#define BB 1024
#define LL 200
#define HH 512
#define NOUT 5
#define BN_EPS 1e-5f

typedef __attribute__((ext_vector_type(8))) short bf16x8;
typedef __attribute__((ext_vector_type(4))) float f32x4;

static __device__ __forceinline__ unsigned short f2bf(float f) {
    unsigned u = __builtin_bit_cast(unsigned, f);
    unsigned r = (u + 0x7FFF + ((u >> 16) & 1)) >> 16;  // RNE
    return (unsigned short)r;
}

// ---------------- K0: pack W1 -> B-fragment layout, zero ps/pq ---------
// Bpk element index: ((n_tile*16 + kstep)*64 + lane)*8 + (k&7)
//   lane = ((k>>3)&3)*16 + (n&15)
__global__ __launch_bounds__(256) void prep_kernel(const float* __restrict__ W1,
                                                   unsigned short* __restrict__ Bpk,
                                                   float* __restrict__ ps) {
    const int id = blockIdx.x * 256 + threadIdx.x;  // 65536 threads, 4 elems each
    const int base = id * 4;
    const int k = base >> 9;
    const int n = base & 511;
    const float4 w = *(const float4*)&W1[(size_t)k * HH + n];
    const float wv[4] = {w.x, w.y, w.z, w.w};
#pragma unroll
    for (int i = 0; i < 4; ++i) {
        const int ni = n + i;
        const int lane = ((k >> 3) & 3) * 16 + (ni & 15);
        const size_t eidx = (((size_t)(ni >> 4) * 16 + (k >> 5)) * 64 + lane) * 8 + (k & 7);
        Bpk[eidx] = f2bf(wv[i]);
    }
    if (blockIdx.x == 0) {  // zero ps/pq (1024 floats contiguous)
        ((float4*)ps)[threadIdx.x] = make_float4(0.f, 0.f, 0.f, 0.f);
    }
}

// ---------------- K1: ragged embedding-bag mean -> A-fragment pack -----
__global__ __launch_bounds__(256) void pool_kernel(const int* __restrict__ tokens,
                                                   const int* __restrict__ lengths,
                                                   const float* __restrict__ emb,
                                                   unsigned short* __restrict__ Apk) {
    __shared__ int toks[LL];
    __shared__ float part[128][4];
    const int b = blockIdx.x;
    const int tid = threadIdx.x;
    const int len = lengths[b];
    for (int t = tid; t < len; t += 256) toks[t] = tokens[b * LL + t];
    __syncthreads();
    const int g = tid >> 7;      // token group 0/1
    const int q = tid & 127;     // column quad
    const int c = q * 4;
    float ax = 0.f, ay = 0.f, az = 0.f, aw = 0.f;
    int t = g;
    for (; t + 14 < len; t += 16) {
#pragma unroll
        for (int u = 0; u < 8; ++u) {
            const float4 v = *(const float4*)&emb[(size_t)toks[t + 2 * u] * HH + c];
            ax += v.x; ay += v.y; az += v.z; aw += v.w;
        }
    }
    for (; t < len; t += 2) {
        const float4 v = *(const float4*)&emb[(size_t)toks[t] * HH + c];
        ax += v.x; ay += v.y; az += v.z; aw += v.w;
    }
    if (g == 1) {
        part[q][0] = ax; part[q][1] = ay; part[q][2] = az; part[q][3] = aw;
    }
    __syncthreads();
    if (g == 0) {
        const float inv = 1.f / (float)len;
        // A-pack: element ((m_tile*16 + kstep)*64 + lane)*8 + (k&7),
        //   m_tile=b>>4, kstep=c>>5, lane=((c>>3)&3)*16+(b&15)
        const int lane = ((c >> 3) & 3) * 16 + (b & 15);
        const size_t eidx = (((size_t)(b >> 4) * 16 + (c >> 5)) * 64 + lane) * 8 + (c & 7);
        ushort4 o;
        o.x = f2bf((ax + part[q][0]) * inv);
        o.y = f2bf((ay + part[q][1]) * inv);
        o.z = f2bf((az + part[q][2]) * inv);
        o.w = f2bf((aw + part[q][3]) * inv);
        *(ushort4*)&Apk[eidx] = o;
    }
}

// ---------------- K2: h = A@W1 + b1 via MFMA, fused column stats -------
// Block 64x64 (4 waves, 2x2; wave tile 32x32 = 2x2 16x16 frags). Grid (8,16).
__global__ __launch_bounds__(256) void gemm1_mfma(const unsigned short* __restrict__ Apk,
                                                  const unsigned short* __restrict__ Bpk,
                                                  const float* __restrict__ b1,
                                                  float* __restrict__ hpre,
                                                  float* __restrict__ ps,
                                                  float* __restrict__ pq) {
    const int tid = threadIdx.x;
    const int lane = tid & 63;
    const int w = tid >> 6;
    const int mt0 = blockIdx.y * 4 + (w >> 1) * 2;  // 16-row tile index
    const int nt0 = blockIdx.x * 4 + (w & 1) * 2;   // 16-col tile index

    f32x4 acc[2][2];
#pragma unroll
    for (int i = 0; i < 2; ++i)
#pragma unroll
        for (int j = 0; j < 2; ++j) acc[i][j] = (f32x4){0.f, 0.f, 0.f, 0.f};

    const unsigned short* a0p = Apk + ((size_t)(mt0 + 0) * 16 * 64 + lane) * 8;
    const unsigned short* a1p = Apk + ((size_t)(mt0 + 1) * 16 * 64 + lane) * 8;
    const unsigned short* b0p = Bpk + ((size_t)(nt0 + 0) * 16 * 64 + lane) * 8;
    const unsigned short* b1p = Bpk + ((size_t)(nt0 + 1) * 16 * 64 + lane) * 8;
#pragma unroll 4
    for (int ks = 0; ks < 16; ++ks) {
        const bf16x8 a0 = *(const bf16x8*)(a0p + (size_t)ks * 512);
        const bf16x8 a1 = *(const bf16x8*)(a1p + (size_t)ks * 512);
        const bf16x8 bb0 = *(const bf16x8*)(b0p + (size_t)ks * 512);
        const bf16x8 bb1 = *(const bf16x8*)(b1p + (size_t)ks * 512);
        acc[0][0] = __builtin_amdgcn_mfma_f32_16x16x32_bf16(a0, bb0, acc[0][0], 0, 0, 0);
        acc[0][1] = __builtin_amdgcn_mfma_f32_16x16x32_bf16(a0, bb1, acc[0][1], 0, 0, 0);
        acc[1][0] = __builtin_amdgcn_mfma_f32_16x16x32_bf16(a1, bb0, acc[1][0], 0, 0, 0);
        acc[1][1] = __builtin_amdgcn_mfma_f32_16x16x32_bf16(a1, bb1, acc[1][1], 0, 0, 0);
    }

    // Epilogue: +b1, write hpre, per-column sum/sumsq partials.
    const int col0 = nt0 * 16 + (lane & 15);
    const int col1 = col0 + 16;
    const float bias0 = b1[col0];
    const float bias1 = b1[col1];
    const int rbase = (lane >> 4) * 4;
    float s0 = 0.f, q0 = 0.f, s1 = 0.f, q1 = 0.f;
#pragma unroll
    for (int mi = 0; mi < 2; ++mi) {
        const int rowb = (mt0 + mi) * 16 + rbase;
#pragma unroll
        for (int r = 0; r < 4; ++r) {
            const float v0 = acc[mi][0][r] + bias0;
            const float v1 = acc[mi][1][r] + bias1;
            hpre[(size_t)(rowb + r) * HH + col0] = v0;
            hpre[(size_t)(rowb + r) * HH + col1] = v1;
            s0 += v0; q0 += v0 * v0;
            s1 += v1; q1 += v1 * v1;
        }
    }
    s0 += __shfl_xor(s0, 16, 64); s0 += __shfl_xor(s0, 32, 64);
    q0 += __shfl_xor(q0, 16, 64); q0 += __shfl_xor(q0, 32, 64);
    s1 += __shfl_xor(s1, 16, 64); s1 += __shfl_xor(s1, 32, 64);
    q1 += __shfl_xor(q1, 16, 64); q1 += __shfl_xor(q1, 32, 64);
    if (lane < 16) {
        atomicAdd(&ps[col0], s0);
        atomicAdd(&pq[col0], q0);
        atomicAdd(&ps[col1], s1);
        atomicAdd(&pq[col1], q1);
    }
}

// ---------------- K3: BN finalize + ReLU + GEMM2 -----------------------
__global__ __launch_bounds__(256) void bn_out_kernel(const float* __restrict__ Hm,
                                                     const float* __restrict__ ps,
                                                     const float* __restrict__ pq,
                                                     const float* __restrict__ gamma,
                                                     const float* __restrict__ beta,
                                                     const float* __restrict__ W2,
                                                     const float* __restrict__ b2,
                                                     float* __restrict__ out) {
    __shared__ float sscale[HH];
    __shared__ float sshift[HH];
    const int tid = threadIdx.x;
#pragma unroll
    for (int i = 0; i < 2; ++i) {
        const int j = tid + i * 256;
        const float mu = ps[j] * (1.f / (float)BB);
        const float var = pq[j] * (1.f / (float)BB) - mu * mu;
        const float sc = gamma[j] * rsqrtf(var + BN_EPS);
        sscale[j] = sc;
        sshift[j] = beta[j] - mu * sc;
    }
    __syncthreads();
    const int lane = tid & 63;
    const int wave = tid >> 6;
    const int row = blockIdx.x * 4 + wave;
    float w[8][NOUT];
#pragma unroll
    for (int j = 0; j < 8; ++j) {
        const int h = lane + j * 64;
#pragma unroll
        for (int k = 0; k < NOUT; ++k) w[j][k] = W2[h * NOUT + k];
    }
    float a0 = 0.f, a1 = 0.f, a2 = 0.f, a3 = 0.f, a4 = 0.f;
#pragma unroll
    for (int j = 0; j < 8; ++j) {
        const int h = lane + j * 64;
        float y = Hm[(size_t)row * HH + h] * sscale[h] + sshift[h];
        y = fmaxf(y, 0.f);
        a0 += y * w[j][0]; a1 += y * w[j][1]; a2 += y * w[j][2];
        a3 += y * w[j][3]; a4 += y * w[j][4];
    }
#pragma unroll
    for (int off = 32; off > 0; off >>= 1) {
        a0 += __shfl_down(a0, off, 64);
        a1 += __shfl_down(a1, off, 64);
        a2 += __shfl_down(a2, off, 64);
        a3 += __shfl_down(a3, off, 64);
        a4 += __shfl_down(a4, off, 64);
    }
    if (lane == 0) {
        out[row * NOUT + 0] = a0 + b2[0];
        out[row * NOUT + 1] = a1 + b2[1];
        out[row * NOUT + 2] = a2 + b2[2];
        out[row * NOUT + 3] = a3 + b2[3];
        out[row * NOUT + 4] = a4 + b2[4];
    }
}

extern "C" void kernel_launch(void* const* d_in, const int* in_sizes, int n_in,
                              void* d_out, int out_size, void* d_ws, size_t ws_size,
                              hipStream_t stream) {
    const int*   tokens  = (const int*)d_in[0];
    const int*   lengths = (const int*)d_in[1];
    const float* emb     = (const float*)d_in[2];
    const float* W1      = (const float*)d_in[3];
    const float* b1      = (const float*)d_in[4];
    const float* gamma   = (const float*)d_in[5];
    const float* beta    = (const float*)d_in[6];
    const float* W2      = (const float*)d_in[7];
    const float* b2      = (const float*)d_in[8];
    float* out = (float*)d_out;

    float* ws   = (float*)d_ws;
    float* hpre = ws;                          // 1024*512 f32
    float* ps   = hpre + BB * HH;              // 512
    float* pq   = ps + HH;                     // 512
    unsigned short* Apk = (unsigned short*)(pq + HH);  // 1024*512 bf16
    unsigned short* Bpk = Apk + BB * HH;               // 512*512 bf16

    prep_kernel<<<256, 256, 0, stream>>>(W1, Bpk, ps);
    pool_kernel<<<BB, 256, 0, stream>>>(tokens, lengths, emb, Apk);
    gemm1_mfma<<<dim3(HH / 64, BB / 64), 256, 0, stream>>>(Apk, Bpk, b1, hpre, ps, pq);
    bn_out_kernel<<<BB / 4, 256, 0, stream>>>(hpre, ps, pq, gamma, beta, W2, b2, out);
}

// Round 4
// 52.603 us; speedup vs baseline: 1.5393x; 1.0903x over previous
//
#include <hip/hip_runtime.h>

#define BB 1024
#define LL 200
#define HH 512
#define NOUT 5
#define NSUB 4
#define BN_EPS 1e-5f

typedef __attribute__((ext_vector_type(8))) short bf16x8;
typedef __attribute__((ext_vector_type(4))) float f32x4;

static __device__ __forceinline__ unsigned short f2bf(float f) {
    unsigned u = __builtin_bit_cast(unsigned, f);
    unsigned r = (u + 0x7FFF + ((u >> 16) & 1)) >> 16;  // RNE
    return (unsigned short)r;
}

// ---------------- K1: pooled partial sums, 4 token-subsets/example -----
// Block bid = b*4 + s handles tokens t ≡ {2s, 2s+1} (mod 8) of example b.
// 256 thr: g=tid>>7 picks parity, q=tid&127 owns 4 cols (float4/lane).
__global__ __launch_bounds__(256) void pool_partial(const int* __restrict__ tokens,
                                                    const int* __restrict__ lengths,
                                                    const float* __restrict__ emb,
                                                    float* __restrict__ part) {
    __shared__ int toks[LL];
    __shared__ float red[128][4];
    const int bid = blockIdx.x;
    const int b = bid >> 2;
    const int s = bid & 3;
    const int tid = threadIdx.x;
    const int len = lengths[b];
    for (int t = tid; t < len; t += 256) toks[t] = tokens[b * LL + t];
    __syncthreads();
    const int g = tid >> 7;
    const int q = tid & 127;
    const int c = q * 4;
    float ax = 0.f, ay = 0.f, az = 0.f, aw = 0.f;
    int t = s * 2 + g;
    for (; t + 56 < len; t += 64) {  // 8 independent gathers in flight
#pragma unroll
        for (int u = 0; u < 8; ++u) {
            const float4 v = *(const float4*)&emb[(size_t)toks[t + 8 * u] * HH + c];
            ax += v.x; ay += v.y; az += v.z; aw += v.w;
        }
    }
    for (; t < len; t += 8) {
        const float4 v = *(const float4*)&emb[(size_t)toks[t] * HH + c];
        ax += v.x; ay += v.y; az += v.z; aw += v.w;
    }
    if (g == 1) {
        red[q][0] = ax; red[q][1] = ay; red[q][2] = az; red[q][3] = aw;
    }
    __syncthreads();
    if (g == 0) {
        float4 o;
        o.x = ax + red[q][0];
        o.y = ay + red[q][1];
        o.z = az + red[q][2];
        o.w = aw + red[q][3];
        *(float4*)&part[(size_t)bid * HH + c] = o;
    }
}

// ---------------- K2: reduce partials -> Apk pack; W1 -> Bpk; zero ps --
__global__ __launch_bounds__(256) void pack_kernel(const float* __restrict__ part,
                                                   const int* __restrict__ lengths,
                                                   const float* __restrict__ W1,
                                                   unsigned short* __restrict__ Apk,
                                                   unsigned short* __restrict__ Bpk,
                                                   float* __restrict__ ps) {
    const int bid = blockIdx.x;
    const int tid = threadIdx.x;
    if (bid < 512) {
        const int idx = bid * 256 + tid;  // 131072 = 1024 examples * 128 quads
        const int b = idx >> 7;
        const int q = idx & 127;
        const int c = q * 4;
        float4 a = *(const float4*)&part[((size_t)(b * 4 + 0)) * HH + c];
        const float4 p1 = *(const float4*)&part[((size_t)(b * 4 + 1)) * HH + c];
        const float4 p2 = *(const float4*)&part[((size_t)(b * 4 + 2)) * HH + c];
        const float4 p3 = *(const float4*)&part[((size_t)(b * 4 + 3)) * HH + c];
        a.x += p1.x + p2.x + p3.x;
        a.y += p1.y + p2.y + p3.y;
        a.z += p1.z + p2.z + p3.z;
        a.w += p1.w + p2.w + p3.w;
        const float inv = 1.f / (float)lengths[b];
        // A-fragment pack (same mapping as verified R3 kernel):
        const int lane = ((c >> 3) & 3) * 16 + (b & 15);
        const size_t eidx = (((size_t)(b >> 4) * 16 + (c >> 5)) * 64 + lane) * 8 + (c & 7);
        ushort4 o;
        o.x = f2bf(a.x * inv); o.y = f2bf(a.y * inv);
        o.z = f2bf(a.z * inv); o.w = f2bf(a.w * inv);
        *(ushort4*)&Apk[eidx] = o;
    } else {
        const int id = (bid - 512) * 256 + tid;  // 65536 threads, 4 elems each
        const int base = id * 4;
        const int k = base >> 9;
        const int n = base & 511;
        const float4 w = *(const float4*)&W1[(size_t)k * HH + n];
        const float wv[4] = {w.x, w.y, w.z, w.w};
#pragma unroll
        for (int i = 0; i < 4; ++i) {
            const int ni = n + i;
            const int lane = ((k >> 3) & 3) * 16 + (ni & 15);
            const size_t eidx = (((size_t)(ni >> 4) * 16 + (k >> 5)) * 64 + lane) * 8 + (k & 7);
            Bpk[eidx] = f2bf(wv[i]);
        }
        if (bid == 512) {  // zero ps+pq (1024 contiguous floats)
            ((float4*)ps)[tid] = make_float4(0.f, 0.f, 0.f, 0.f);
        }
    }
}

// ---------------- K3: h = A@W1 + b1 via MFMA, fused column stats -------
__global__ __launch_bounds__(256) void gemm1_mfma(const unsigned short* __restrict__ Apk,
                                                  const unsigned short* __restrict__ Bpk,
                                                  const float* __restrict__ b1,
                                                  float* __restrict__ hpre,
                                                  float* __restrict__ ps,
                                                  float* __restrict__ pq) {
    const int tid = threadIdx.x;
    const int lane = tid & 63;
    const int w = tid >> 6;
    const int mt0 = blockIdx.y * 4 + (w >> 1) * 2;
    const int nt0 = blockIdx.x * 4 + (w & 1) * 2;

    f32x4 acc[2][2];
#pragma unroll
    for (int i = 0; i < 2; ++i)
#pragma unroll
        for (int j = 0; j < 2; ++j) acc[i][j] = (f32x4){0.f, 0.f, 0.f, 0.f};

    const unsigned short* a0p = Apk + ((size_t)(mt0 + 0) * 16 * 64 + lane) * 8;
    const unsigned short* a1p = Apk + ((size_t)(mt0 + 1) * 16 * 64 + lane) * 8;
    const unsigned short* b0p = Bpk + ((size_t)(nt0 + 0) * 16 * 64 + lane) * 8;
    const unsigned short* b1p = Bpk + ((size_t)(nt0 + 1) * 16 * 64 + lane) * 8;
#pragma unroll 4
    for (int ks = 0; ks < 16; ++ks) {
        const bf16x8 a0 = *(const bf16x8*)(a0p + (size_t)ks * 512);
        const bf16x8 a1 = *(const bf16x8*)(a1p + (size_t)ks * 512);
        const bf16x8 bb0 = *(const bf16x8*)(b0p + (size_t)ks * 512);
        const bf16x8 bb1 = *(const bf16x8*)(b1p + (size_t)ks * 512);
        acc[0][0] = __builtin_amdgcn_mfma_f32_16x16x32_bf16(a0, bb0, acc[0][0], 0, 0, 0);
        acc[0][1] = __builtin_amdgcn_mfma_f32_16x16x32_bf16(a0, bb1, acc[0][1], 0, 0, 0);
        acc[1][0] = __builtin_amdgcn_mfma_f32_16x16x32_bf16(a1, bb0, acc[1][0], 0, 0, 0);
        acc[1][1] = __builtin_amdgcn_mfma_f32_16x16x32_bf16(a1, bb1, acc[1][1], 0, 0, 0);
    }

    const int col0 = nt0 * 16 + (lane & 15);
    const int col1 = col0 + 16;
    const float bias0 = b1[col0];
    const float bias1 = b1[col1];
    const int rbase = (lane >> 4) * 4;
    float s0 = 0.f, q0 = 0.f, s1 = 0.f, q1 = 0.f;
#pragma unroll
    for (int mi = 0; mi < 2; ++mi) {
        const int rowb = (mt0 + mi) * 16 + rbase;
#pragma unroll
        for (int r = 0; r < 4; ++r) {
            const float v0 = acc[mi][0][r] + bias0;
            const float v1 = acc[mi][1][r] + bias1;
            hpre[(size_t)(rowb + r) * HH + col0] = v0;
            hpre[(size_t)(rowb + r) * HH + col1] = v1;
            s0 += v0; q0 += v0 * v0;
            s1 += v1; q1 += v1 * v1;
        }
    }
    s0 += __shfl_xor(s0, 16, 64); s0 += __shfl_xor(s0, 32, 64);
    q0 += __shfl_xor(q0, 16, 64); q0 += __shfl_xor(q0, 32, 64);
    s1 += __shfl_xor(s1, 16, 64); s1 += __shfl_xor(s1, 32, 64);
    q1 += __shfl_xor(q1, 16, 64); q1 += __shfl_xor(q1, 32, 64);
    if (lane < 16) {
        atomicAdd(&ps[col0], s0);
        atomicAdd(&pq[col0], q0);
        atomicAdd(&ps[col1], s1);
        atomicAdd(&pq[col1], q1);
    }
}

// ---------------- K4: BN finalize + ReLU + GEMM2 -----------------------
__global__ __launch_bounds__(256) void bn_out_kernel(const float* __restrict__ Hm,
                                                     const float* __restrict__ ps,
                                                     const float* __restrict__ pq,
                                                     const float* __restrict__ gamma,
                                                     const float* __restrict__ beta,
                                                     const float* __restrict__ W2,
                                                     const float* __restrict__ b2,
                                                     float* __restrict__ out) {
    __shared__ float sscale[HH];
    __shared__ float sshift[HH];
    const int tid = threadIdx.x;
#pragma unroll
    for (int i = 0; i < 2; ++i) {
        const int j = tid + i * 256;
        const float mu = ps[j] * (1.f / (float)BB);
        const float var = pq[j] * (1.f / (float)BB) - mu * mu;
        const float sc = gamma[j] * rsqrtf(var + BN_EPS);
        sscale[j] = sc;
        sshift[j] = beta[j] - mu * sc;
    }
    __syncthreads();
    const int lane = tid & 63;
    const int wave = tid >> 6;
    const int row = blockIdx.x * 4 + wave;
    float w[8][NOUT];
#pragma unroll
    for (int j = 0; j < 8; ++j) {
        const int h = lane + j * 64;
#pragma unroll
        for (int k = 0; k < NOUT; ++k) w[j][k] = W2[h * NOUT + k];
    }
    float a0 = 0.f, a1 = 0.f, a2 = 0.f, a3 = 0.f, a4 = 0.f;
#pragma unroll
    for (int j = 0; j < 8; ++j) {
        const int h = lane + j * 64;
        float y = Hm[(size_t)row * HH + h] * sscale[h] + sshift[h];
        y = fmaxf(y, 0.f);
        a0 += y * w[j][0]; a1 += y * w[j][1]; a2 += y * w[j][2];
        a3 += y * w[j][3]; a4 += y * w[j][4];
    }
#pragma unroll
    for (int off = 32; off > 0; off >>= 1) {
        a0 += __shfl_down(a0, off, 64);
        a1 += __shfl_down(a1, off, 64);
        a2 += __shfl_down(a2, off, 64);
        a3 += __shfl_down(a3, off, 64);
        a4 += __shfl_down(a4, off, 64);
    }
    if (lane == 0) {
        out[row * NOUT + 0] = a0 + b2[0];
        out[row * NOUT + 1] = a1 + b2[1];
        out[row * NOUT + 2] = a2 + b2[2];
        out[row * NOUT + 3] = a3 + b2[3];
        out[row * NOUT + 4] = a4 + b2[4];
    }
}

extern "C" void kernel_launch(void* const* d_in, const int* in_sizes, int n_in,
                              void* d_out, int out_size, void* d_ws, size_t ws_size,
                              hipStream_t stream) {
    const int*   tokens  = (const int*)d_in[0];
    const int*   lengths = (const int*)d_in[1];
    const float* emb     = (const float*)d_in[2];
    const float* W1      = (const float*)d_in[3];
    const float* b1      = (const float*)d_in[4];
    const float* gamma   = (const float*)d_in[5];
    const float* beta    = (const float*)d_in[6];
    const float* W2      = (const float*)d_in[7];
    const float* b2      = (const float*)d_in[8];
    float* out = (float*)d_out;

    float* ws   = (float*)d_ws;
    float* hpre = ws;                          // 1024*512 f32
    float* ps   = hpre + BB * HH;              // 512
    float* pq   = ps + HH;                     // 512
    float* part = pq + HH;                     // 4096*512 f32 (8 MB)
    unsigned short* Apk = (unsigned short*)(part + (size_t)BB * NSUB * HH);
    unsigned short* Bpk = Apk + (size_t)BB * HH;

    pool_partial<<<BB * NSUB, 256, 0, stream>>>(tokens, lengths, emb, part);
    pack_kernel<<<768, 256, 0, stream>>>(part, lengths, W1, Apk, Bpk, ps);
    gemm1_mfma<<<dim3(HH / 64, BB / 64), 256, 0, stream>>>(Apk, Bpk, b1, hpre, ps, pq);
    bn_out_kernel<<<BB / 4, 256, 0, stream>>>(hpre, ps, pq, gamma, beta, W2, b2, out);
}